// Round 1
// baseline (1465.772 us; speedup 1.0000x reference)
//
#include <hip/hip_runtime.h>
#include <hip/hip_bf16.h>
#include <stdint.h>

// CompressedLinear: C[8192,11008] = x[8192,4096] @ (w_int8*scale)[11008,4096]^T + bias
// Strategy: convert x->bf16 and w->bf16 in d_ws, then m97-style 128x128 bf16 MFMA GEMM.

#define M_DIM 8192
#define N_DIM 11008
#define K_DIM 4096

typedef short bf16x8 __attribute__((ext_vector_type(8)));   // 8 bf16 = 4 VGPRs (guide §3)
typedef float f32x4 __attribute__((ext_vector_type(4)));

__device__ __forceinline__ unsigned short f2bf(float f) {
    union { float f; uint32_t u; } c; c.f = f;
    uint32_t u = c.u;
    return (unsigned short)((u + 0x7FFFu + ((u >> 16) & 1u)) >> 16);  // RNE, no NaN inputs
}

__global__ __launch_bounds__(256) void cvt_x_kernel(const float* __restrict__ x,
                                                    unsigned short* __restrict__ o, int n4) {
    int i = blockIdx.x * 256 + threadIdx.x;
    if (i >= n4) return;
    float4 v = ((const float4*)x)[i];
    ushort4 r;
    r.x = f2bf(v.x); r.y = f2bf(v.y); r.z = f2bf(v.z); r.w = f2bf(v.w);
    ((ushort4*)o)[i] = r;
}

__global__ __launch_bounds__(256) void cvt_w_kernel(const int* __restrict__ w,
                                                    unsigned short* __restrict__ o, int n4) {
    int i = blockIdx.x * 256 + threadIdx.x;
    if (i >= n4) return;
    int4 v = ((const int4*)w)[i];
    ushort4 r;  // int8 values are exact in bf16
    r.x = f2bf((float)v.x); r.y = f2bf((float)v.y);
    r.z = f2bf((float)v.z); r.w = f2bf((float)v.w);
    ((ushort4*)o)[i] = r;
}

// async 16B global->LDS (wave-uniform LDS base + lane*16; LDS layout must be
// contiguous in lane order — hence unpadded [row][32] tiles)
__device__ __forceinline__ void async16(const void* g, void* l) {
    __builtin_amdgcn_global_load_lds((__attribute__((address_space(1))) void*)g,
                                     (__attribute__((address_space(3))) void*)l,
                                     16, 0, 0);
}

__global__ __launch_bounds__(256) void gemm_bf16_kernel(
    const unsigned short* __restrict__ A,   // [M][K] bf16
    const unsigned short* __restrict__ B,   // [N][K] bf16 (B^T layout)
    const float* __restrict__ scale_p,
    const float* __restrict__ bias,
    float* __restrict__ out)                // [M][N] fp32
{
    __shared__ unsigned short As[128 * 32];
    __shared__ unsigned short Bs[128 * 32];

    const int t    = threadIdx.x;
    const int bn   = blockIdx.x;    // 0..85
    const int bm   = blockIdx.y;    // 0..63
    const int lane = t & 63;
    const int w    = t >> 6;
    const int wr   = w >> 1;        // wave row (0..1)
    const int wc   = w & 1;         // wave col (0..1)
    const int quad = lane >> 4;     // 0..3
    const int l16  = lane & 15;

    f32x4 acc[4][4];
#pragma unroll
    for (int i = 0; i < 4; i++)
#pragma unroll
        for (int j = 0; j < 4; j++)
            acc[i][j] = (f32x4){0.f, 0.f, 0.f, 0.f};

    // staging: idx in [0,512): row = idx>>2 (0..127), col8 = (idx&3)*8
    const int row0 = t >> 2;
    const int row1 = (t + 256) >> 2;
    const int col8 = (t & 3) * 8;

    const unsigned short* Ab = A + (size_t)(bm * 128) * K_DIM;
    const unsigned short* Bb = B + (size_t)(bn * 128) * K_DIM;

    for (int kt = 0; kt < K_DIM / 32; kt++) {
        const int k0 = kt * 32;
        async16(Ab + (size_t)row0 * K_DIM + k0 + col8, (char*)As + t * 16);
        async16(Ab + (size_t)row1 * K_DIM + k0 + col8, (char*)As + (t + 256) * 16);
        async16(Bb + (size_t)row0 * K_DIM + k0 + col8, (char*)Bs + t * 16);
        async16(Bb + (size_t)row1 * K_DIM + k0 + col8, (char*)Bs + (t + 256) * 16);
        __syncthreads();   // drains vmcnt before barrier (m97 structure)

        bf16x8 af[4], bfr[4];
#pragma unroll
        for (int i = 0; i < 4; i++)
            af[i] = *(const bf16x8*)((const char*)As +
                     (((wr * 64 + i * 16 + l16) * 32 + quad * 8) * 2));
#pragma unroll
        for (int j = 0; j < 4; j++)
            bfr[j] = *(const bf16x8*)((const char*)Bs +
                     (((wc * 64 + j * 16 + l16) * 32 + quad * 8) * 2));

#pragma unroll
        for (int i = 0; i < 4; i++)
#pragma unroll
            for (int j = 0; j < 4; j++)
                acc[i][j] = __builtin_amdgcn_mfma_f32_16x16x32_bf16(
                    af[i], bfr[j], acc[i][j], 0, 0, 0);
        __syncthreads();   // LDS reads done before next stage overwrites
    }

    // epilogue: C/D mapping col=lane&15, row=quad*4+reg  (m89-verified)
    const float scale = *scale_p;
    const int gcol_base = bn * 128 + wc * 64 + l16;
    float bvals[4];
#pragma unroll
    for (int j = 0; j < 4; j++) bvals[j] = bias[gcol_base + j * 16];

#pragma unroll
    for (int i = 0; i < 4; i++) {
        const int grow0 = bm * 128 + wr * 64 + i * 16 + quad * 4;
#pragma unroll
        for (int r = 0; r < 4; r++) {
            float* orow = out + (size_t)(grow0 + r) * N_DIM + gcol_base;
#pragma unroll
            for (int j = 0; j < 4; j++)
                orow[j * 16] = acc[i][j][r] * scale + bvals[j];
        }
    }
}

// correctness fallback if ws is too small (should not trigger: needs ~157 MB)
__global__ __launch_bounds__(256) void naive_kernel(
    const float* __restrict__ x, const int* __restrict__ w8,
    const float* __restrict__ scale_p, const float* __restrict__ bias,
    float* __restrict__ out)
{
    size_t idx = (size_t)blockIdx.x * 256 + threadIdx.x;
    if (idx >= (size_t)M_DIM * N_DIM) return;
    int n = (int)(idx % N_DIM);
    size_t m = idx / N_DIM;
    const float* xr = x + m * K_DIM;
    const int* wr = w8 + (size_t)n * K_DIM;
    float acc = 0.f;
    for (int k = 0; k < K_DIM; k++) acc += xr[k] * (float)wr[k];
    out[idx] = acc * (*scale_p) + bias[n];
}

extern "C" void kernel_launch(void* const* d_in, const int* in_sizes, int n_in,
                              void* d_out, int out_size, void* d_ws, size_t ws_size,
                              hipStream_t stream) {
    const float* x     = (const float*)d_in[0];
    const int*   w8    = (const int*)d_in[1];
    const float* scale = (const float*)d_in[2];
    const float* bias  = (const float*)d_in[3];
    float* out = (float*)d_out;

    const size_t a_bytes = (size_t)M_DIM * K_DIM * 2;   // 67,108,864
    const size_t b_bytes = (size_t)N_DIM * K_DIM * 2;   // 90,177,536

    if (ws_size >= a_bytes + b_bytes) {
        unsigned short* a_bf = (unsigned short*)d_ws;
        unsigned short* b_bf = (unsigned short*)((char*)d_ws + a_bytes);
        const int nx4 = M_DIM * K_DIM / 4;   // 8,388,608  -> 32768 blocks
        const int nw4 = N_DIM * K_DIM / 4;   // 11,272,192 -> 44032 blocks
        cvt_x_kernel<<<nx4 / 256, 256, 0, stream>>>(x, a_bf, nx4);
        cvt_w_kernel<<<nw4 / 256, 256, 0, stream>>>(w8, b_bf, nw4);
        gemm_bf16_kernel<<<dim3(N_DIM / 128, M_DIM / 128), 256, 0, stream>>>(
            a_bf, b_bf, scale, bias, out);
    } else {
        size_t total = (size_t)M_DIM * N_DIM;
        naive_kernel<<<(unsigned)((total + 255) / 256), 256, 0, stream>>>(
            x, w8, scale, bias, out);
    }
}